// Round 1
// baseline (694.479 us; speedup 1.0000x reference)
//
#include <hip/hip_runtime.h>
#include <math.h>

#define NN   1024
#define HIDD 256
#define NH   8
#define HD   32
#define NW   32   // 1024 bits / 32 per word

__device__ __forceinline__ float silu_f(float x) {
    return x / (1.0f + __expf(-x));
}

// ---------------- path propagation (bit-packed boolean) ----------------

__global__ void scatter_edges_kernel(const int* __restrict__ ei, int E,
                                     unsigned* __restrict__ prow,
                                     unsigned* __restrict__ acol) {
    int e = blockIdx.x * 256 + threadIdx.x;
    if (e >= E) return;
    int r = ei[e], c = ei[E + e];
    if ((unsigned)r < NN && (unsigned)c < NN) {
        atomicOr(&prow[r * NW + (c >> 5)], 1u << (c & 31));
        atomicOr(&acol[c * NW + (r >> 5)], 1u << (r & 31));
    }
}

// out[i,j] = in[i,j] & (OR_k in[i,k] & adj[k,j])
__global__ __launch_bounds__(256)
void path_iter_kernel(const unsigned* __restrict__ pin,
                      const unsigned* __restrict__ acol,
                      unsigned* __restrict__ pout) {
    __shared__ unsigned pr[8][NW];
    int t  = threadIdx.x;
    int ty = t >> 5;     // local row 0..7
    int wj = t & 31;     // output word index
    int i  = blockIdx.x * 8 + ty;
    pr[ty][wj] = pin[i * NW + wj];
    __syncthreads();
    unsigned inw  = pr[ty][wj];
    unsigned outw = 0u;
    for (int b = 0; b < 32; ++b) {
        int j = (wj << 5) | b;
        const unsigned* ac = &acol[j * NW];
        unsigned acc = 0u;
        #pragma unroll
        for (int w = 0; w < NW; ++w) acc |= pr[ty][w] & ac[w];
        outw |= (acc ? 1u : 0u) << b;
    }
    pout[i * NW + wj] = inw & outw;
}

// topo MLP evaluated at x in {0,1}: t01[x*8+h]
__global__ void topo_t01_kernel(const float* __restrict__ w1, const float* __restrict__ b1,
                                const float* __restrict__ w2, const float* __restrict__ b2,
                                float* __restrict__ t01) {
    int t = threadIdx.x;
    if (t >= 16) return;
    int h = t & 7;
    float x = (t >> 3) ? 1.0f : 0.0f;
    float acc = b2[h];
    for (int c = 0; c < 32; ++c)
        acc += silu_f(x * w1[c] + b1[c]) * w2[c * 8 + h];
    t01[t] = acc;
}

// ---------------- generic fp32 tiled GEMM: C = act(A@B + bias) ----------------
// A logically [M,K] row-major; split at splitK between A1 (stride splitK) and
// A2 (stride K-splitK). B [K,N] row-major. 64x64 tile, 16x16 threads, 4x4/thread.

__global__ __launch_bounds__(256)
void gemm_kernel(const float* __restrict__ A1, const float* __restrict__ A2, int splitK,
                 const float* __restrict__ B, const float* __restrict__ bias,
                 float* __restrict__ C, int Nn, int K, int act) {
    __shared__ float As[16][65];
    __shared__ float Bs[16][64];
    int t  = threadIdx.x;
    int tx = t & 15, ty = t >> 4;
    int i0 = blockIdx.y * 64, j0 = blockIdx.x * 64;
    int lda1 = splitK;
    int lda2 = K - splitK;
    float c[4][4] = {};
    for (int k0 = 0; k0 < K; k0 += 16) {
        const float* Abase;
        int lda;
        if (k0 < splitK) { Abase = A1 + k0;            lda = lda1; }
        else             { Abase = A2 + (k0 - splitK); lda = lda2; }
        #pragma unroll
        for (int l = 0; l < 4; ++l) {
            int idx = t + l * 256;
            int im = idx >> 4, kk = idx & 15;
            As[kk][im] = Abase[(i0 + im) * lda + kk];
        }
        #pragma unroll
        for (int l = 0; l < 4; ++l) {
            int idx = t + l * 256;
            int kk = idx >> 6, jn = idx & 63;
            Bs[kk][jn] = B[(k0 + kk) * Nn + j0 + jn];
        }
        __syncthreads();
        #pragma unroll
        for (int kk = 0; kk < 16; ++kk) {
            float a[4], b[4];
            #pragma unroll
            for (int i = 0; i < 4; ++i) a[i] = As[kk][ty + 16 * i];
            #pragma unroll
            for (int j = 0; j < 4; ++j) b[j] = Bs[kk][tx + 16 * j];
            #pragma unroll
            for (int i = 0; i < 4; ++i)
                #pragma unroll
                for (int j = 0; j < 4; ++j)
                    c[i][j] += a[i] * b[j];
        }
        __syncthreads();
    }
    #pragma unroll
    for (int i = 0; i < 4; ++i) {
        int row = i0 + ty + 16 * i;
        #pragma unroll
        for (int j = 0; j < 4; ++j) {
            int col = j0 + tx + 16 * j;
            float v = c[i][j] + (bias ? bias[col] : 0.0f);
            if (act == 1) v = silu_f(v);
            C[row * (long)Nn + col] = v;
        }
    }
}

// ---------------- gate logits + 2-way softmax ----------------

__global__ void gate_final_kernel(const float* __restrict__ gh, const float* __restrict__ w2,
                                  const float* __restrict__ b2, float* __restrict__ gate) {
    int n = blockIdx.x * blockDim.x + threadIdx.x;
    if (n >= NN) return;
    const float* row = gh + (long)n * 1024;
    float l0 = b2[0], l1 = b2[1];
    for (int j = 0; j < 1024; ++j) {
        float x = row[j];
        l0 += x * w2[2 * j];
        l1 += x * w2[2 * j + 1];
    }
    float mx = fmaxf(l0, l1);
    float e0 = __expf(l0 - mx), e1 = __expf(l1 - mx);
    float inv = 1.0f / (e0 + e1);
    gate[2 * n]     = e0 * inv;
    gate[2 * n + 1] = e1 * inv;
}

// ---------------- fused attention: scores + biases + softmax + PV ----------------
// one block per src row n

__global__ __launch_bounds__(256)
void attn_kernel(const float* __restrict__ q, const float* __restrict__ k,
                 const float* __restrict__ v, const float* __restrict__ pos,
                 const float* __restrict__ gate, const unsigned* __restrict__ pbits,
                 const float* __restrict__ t01,
                 const float* __restrict__ gw1, const float* __restrict__ gb1,
                 const float* __restrict__ gw2, const float* __restrict__ gb2,
                 float* __restrict__ out) {
    __shared__ float s[NH][NN];          // 32 KB scores
    __shared__ float qs[HIDD];
    __shared__ float w1s[32], b1s[32], w2s[256], b2s[8], t01s[16];
    __shared__ unsigned prow[NW];
    __shared__ float posn[3];
    int n = blockIdx.x;
    int t = threadIdx.x;
    qs[t]  = q[n * HIDD + t];
    w2s[t] = gw2[t];
    if (t < 32) { w1s[t] = gw1[t]; b1s[t] = gb1[t]; prow[t] = pbits[n * NW + t]; }
    if (t < 16) t01s[t] = t01[t];
    if (t < 8)  b2s[t] = gb2[t];
    if (t < 3)  posn[t] = pos[n * 3 + t];
    __syncthreads();
    float g0 = gate[2 * n], g1 = gate[2 * n + 1];
    const float scale = 0.17677669529663687f;  // 1/sqrt(32)

    for (int rep = 0; rep < 4; ++rep) {
        int m = t + rep * 256;
        float dx = posn[0] - pos[m * 3];
        float dy = posn[1] - pos[m * 3 + 1];
        float dz = posn[2] - pos[m * 3 + 2];
        float d2 = dx * dx + dy * dy + dz * dz;
        float d  = sqrtf(fmaxf(d2, 1e-12f));
        float go[8];
        #pragma unroll
        for (int h = 0; h < 8; ++h) go[h] = b2s[h];
        #pragma unroll 4
        for (int c = 0; c < 32; ++c) {
            float hh = silu_f(d * w1s[c] + b1s[c]);
            #pragma unroll
            for (int h = 0; h < 8; ++h) go[h] += hh * w2s[c * 8 + h];
        }
        float qk[8] = {0.f, 0.f, 0.f, 0.f, 0.f, 0.f, 0.f, 0.f};
        const float4* kr = (const float4*)(k + (long)m * HIDD);
        const float4* q4 = (const float4*)qs;
        #pragma unroll
        for (int i = 0; i < 64; ++i) {
            float4 kv = kr[i];
            float4 qv = q4[i];
            qk[i >> 3] += qv.x * kv.x + qv.y * kv.y + qv.z * kv.z + qv.w * kv.w;
        }
        unsigned pb = (prow[m >> 5] >> (m & 31)) & 1u;
        #pragma unroll
        for (int h = 0; h < 8; ++h) {
            float tb = pb ? t01s[8 + h] : t01s[h];
            s[h][m] = qk[h] * scale + g0 * go[h] + g1 * tb;
        }
    }
    __syncthreads();
    // per-head softmax: head h owned by lanes with t>>5 == h (32 lanes each)
    {
        int h = t >> 5, l = t & 31;
        float mx = -1e30f;
        for (int mm = l; mm < NN; mm += 32) mx = fmaxf(mx, s[h][mm]);
        #pragma unroll
        for (int off = 16; off > 0; off >>= 1) mx = fmaxf(mx, __shfl_xor(mx, off, 64));
        float sum = 0.0f;
        for (int mm = l; mm < NN; mm += 32) {
            float e = __expf(s[h][mm] - mx);
            s[h][mm] = e;
            sum += e;
        }
        #pragma unroll
        for (int off = 16; off > 0; off >>= 1) sum += __shfl_xor(sum, off, 64);
        float inv = 1.0f / sum;
        for (int mm = l; mm < NN; mm += 32) s[h][mm] *= inv;
    }
    __syncthreads();
    // PV: thread t -> output column t = h*32+d
    {
        int h = t >> 5;
        float acc = 0.0f;
        #pragma unroll 4
        for (int m = 0; m < NN; ++m)
            acc += s[h][m] * v[(long)m * HIDD + t];
        out[n * HIDD + t] = acc;
    }
}

// ---------------- residual + LayerNorm ----------------

__global__ __launch_bounds__(256)
void ln_kernel(const float* __restrict__ xres, const float* __restrict__ proj,
               const float* __restrict__ g, const float* __restrict__ b,
               float* __restrict__ out) {
    __shared__ float red[8];
    int n = blockIdx.x, t = threadIdx.x;
    float x = xres[n * HIDD + t] + proj[n * HIDD + t];
    float sg = x;
    #pragma unroll
    for (int off = 32; off > 0; off >>= 1) sg += __shfl_down(sg, off, 64);
    int wid = t >> 6;
    if ((t & 63) == 0) red[wid] = sg;
    __syncthreads();
    float mean = (red[0] + red[1] + red[2] + red[3]) * (1.0f / HIDD);
    float dx = x - mean;
    float s2 = dx * dx;
    #pragma unroll
    for (int off = 32; off > 0; off >>= 1) s2 += __shfl_down(s2, off, 64);
    if ((t & 63) == 0) red[4 + wid] = s2;
    __syncthreads();
    float var = (red[4] + red[5] + red[6] + red[7]) * (1.0f / HIDD);
    out[n * HIDD + t] = dx * rsqrtf(var + 1e-5f) * g[t] + b[t];
}

// ---------------- host ----------------

extern "C" void kernel_launch(void* const* d_in, const int* in_sizes, int n_in,
                              void* d_out, int out_size, void* d_ws, size_t ws_size,
                              hipStream_t stream) {
    const float* src  = (const float*)d_in[0];
    const float* tgt  = (const float*)d_in[1];
    const float* pos  = (const float*)d_in[2];
    const int*   ei   = (const int*)d_in[3];
    const float* Wq   = (const float*)d_in[4];  const float* bq  = (const float*)d_in[5];
    const float* Wk   = (const float*)d_in[6];  const float* bk  = (const float*)d_in[7];
    const float* Wv   = (const float*)d_in[8];  const float* bv  = (const float*)d_in[9];
    const float* gw1  = (const float*)d_in[10]; const float* gb1 = (const float*)d_in[11];
    const float* gw2  = (const float*)d_in[12]; const float* gb2 = (const float*)d_in[13];
    const float* tw1  = (const float*)d_in[14]; const float* tb1 = (const float*)d_in[15];
    const float* tw2  = (const float*)d_in[16]; const float* tb2 = (const float*)d_in[17];
    const float* gaw1 = (const float*)d_in[18]; const float* gab1= (const float*)d_in[19];
    const float* gaw2 = (const float*)d_in[20]; const float* gab2= (const float*)d_in[21];
    const float* Wo   = (const float*)d_in[22]; const float* bo  = (const float*)d_in[23];
    const float* lng  = (const float*)d_in[24]; const float* lnb = (const float*)d_in[25];
    int E = in_sizes[3] / 2;

    char* w = (char*)d_ws;
    unsigned* acol = (unsigned*)w; w += NN * NW * 4;      // 128 KB
    unsigned* p0   = (unsigned*)w; w += NN * NW * 4;      // 128 KB (contiguous with acol)
    unsigned* p1   = (unsigned*)w; w += NN * NW * 4;
    float* qb   = (float*)w; w += NN * HIDD * 4;
    float* kb   = (float*)w; w += NN * HIDD * 4;
    float* vb   = (float*)w; w += NN * HIDD * 4;
    float* gh   = (float*)w; w += (long)NN * 1024 * 4;    // 4 MB
    float* gate = (float*)w; w += NN * 2 * 4;
    float* t01  = (float*)w; w += 64;
    float* aout = (float*)w; w += NN * HIDD * 4;
    float* pout = (float*)w; w += NN * HIDD * 4;

    // adjacency bits (acol + p0 are contiguous -> one memset)
    hipMemsetAsync(acol, 0, 2 * NN * NW * 4, stream);
    scatter_edges_kernel<<<(E + 255) / 256, 256, 0, stream>>>(ei, E, p0, acol);
    path_iter_kernel<<<NN / 8, 256, 0, stream>>>(p0, acol, p1);
    path_iter_kernel<<<NN / 8, 256, 0, stream>>>(p1, acol, p0);
    path_iter_kernel<<<NN / 8, 256, 0, stream>>>(p0, acol, p1);   // final path in p1
    topo_t01_kernel<<<1, 64, 0, stream>>>(tw1, tb1, tw2, tb2, t01);

    dim3 gQ(HIDD / 64, NN / 64);   // 4 x 16
    gemm_kernel<<<gQ, 256, 0, stream>>>(src, src, HIDD, Wq, bq, qb, HIDD, HIDD, 0);
    gemm_kernel<<<gQ, 256, 0, stream>>>(tgt, tgt, HIDD, Wk, bk, kb, HIDD, HIDD, 0);
    gemm_kernel<<<gQ, 256, 0, stream>>>(tgt, tgt, HIDD, Wv, bv, vb, HIDD, HIDD, 0);

    dim3 gG(1024 / 64, NN / 64);   // 16 x 16
    gemm_kernel<<<gG, 256, 0, stream>>>(src, tgt, HIDD, gaw1, gab1, gh, 1024, 512, 1);
    gate_final_kernel<<<4, 256, 0, stream>>>(gh, gaw2, gab2, gate);

    attn_kernel<<<NN, 256, 0, stream>>>(qb, kb, vb, pos, gate, p1, t01,
                                        gw1, gb1, gw2, gb2, aout);

    gemm_kernel<<<gQ, 256, 0, stream>>>(aout, aout, HIDD, Wo, bo, pout, HIDD, HIDD, 0);
    ln_kernel<<<NN, 256, 0, stream>>>(src, pout, lng, lnb, (float*)d_out);
}

// Round 2
// 371.308 us; speedup vs baseline: 1.8704x; 1.8704x over previous
//
#include <hip/hip_runtime.h>
#include <math.h>

#define NN   1024
#define HIDD 256
#define NH   8
#define HD   32
#define NW   32   // 1024 bits / 32 per word

__device__ __forceinline__ float silu_f(float x) {
    return x / (1.0f + __expf(-x));
}

// ---------------- path propagation (bit-packed boolean) ----------------

__global__ void scatter_edges_kernel(const int* __restrict__ ei, int E,
                                     unsigned* __restrict__ prow,
                                     unsigned* __restrict__ acol) {
    int e = blockIdx.x * 256 + threadIdx.x;
    if (e >= E) return;
    int r = ei[e], c = ei[E + e];
    if ((unsigned)r < NN && (unsigned)c < NN) {
        atomicOr(&prow[r * NW + (c >> 5)], 1u << (c & 31));
        atomicOr(&acol[c * NW + (r >> 5)], 1u << (r & 31));
    }
}

// out[i,j] = in[i,j] & (OR_k in[i,k] & adj[k,j])
__global__ __launch_bounds__(256)
void path_iter_kernel(const unsigned* __restrict__ pin,
                      const unsigned* __restrict__ acol,
                      unsigned* __restrict__ pout) {
    __shared__ unsigned pr[8][NW];
    int t  = threadIdx.x;
    int ty = t >> 5;     // local row 0..7
    int wj = t & 31;     // output word index
    int i  = blockIdx.x * 8 + ty;
    pr[ty][wj] = pin[i * NW + wj];
    __syncthreads();
    unsigned inw  = pr[ty][wj];
    unsigned outw = 0u;
    for (int b = 0; b < 32; ++b) {
        int j = (wj << 5) | b;
        const unsigned* ac = &acol[j * NW];
        unsigned acc = 0u;
        #pragma unroll
        for (int w = 0; w < NW; ++w) acc |= pr[ty][w] & ac[w];
        outw |= (acc ? 1u : 0u) << b;
    }
    pout[i * NW + wj] = inw & outw;
}

// topo MLP evaluated at x in {0,1}: t01[x*8+h]
__global__ void topo_t01_kernel(const float* __restrict__ w1, const float* __restrict__ b1,
                                const float* __restrict__ w2, const float* __restrict__ b2,
                                float* __restrict__ t01) {
    int t = threadIdx.x;
    if (t >= 16) return;
    int h = t & 7;
    float x = (t >> 3) ? 1.0f : 0.0f;
    float acc = b2[h];
    for (int c = 0; c < 32; ++c)
        acc += silu_f(x * w1[c] + b1[c]) * w2[c * 8 + h];
    t01[t] = acc;
}

// ---------------- shared SGEMM tile machinery ----------------
// 64x64 tile, 256 threads, 4x4 per thread on CONSECUTIVE rows/cols so LDS
// reads are ds_read_b128. A logically [M,K] row-major split at splitK.

__device__ __forceinline__ void gemm_tile(const float* __restrict__ A1,
                                          const float* __restrict__ A2, int splitK,
                                          const float* __restrict__ B,
                                          int Nn, int K, int i0, int j0, int t,
                                          float (&c)[4][4],
                                          float As[16][68], float Bs[16][68]) {
    int tx = t & 15, ty = t >> 4;
    for (int k0 = 0; k0 < K; k0 += 16) {
        const float* Ab; int lda;
        if (k0 < splitK) { Ab = A1 + k0;            lda = splitK; }
        else             { Ab = A2 + (k0 - splitK); lda = K - splitK; }
        #pragma unroll
        for (int l = 0; l < 4; ++l) {
            int idx = t + l * 256;
            int im = idx >> 4, kk = idx & 15;
            As[kk][im] = Ab[(i0 + im) * lda + kk];
        }
        #pragma unroll
        for (int l = 0; l < 4; ++l) {
            int idx = t + l * 256;
            int kk = idx >> 6, jn = idx & 63;
            Bs[kk][jn] = B[(k0 + kk) * (long)Nn + j0 + jn];
        }
        __syncthreads();
        #pragma unroll
        for (int kk = 0; kk < 16; ++kk) {
            float4 a4 = *(const float4*)&As[kk][ty * 4];
            float4 b4 = *(const float4*)&Bs[kk][tx * 4];
            float av[4] = {a4.x, a4.y, a4.z, a4.w};
            float bv[4] = {b4.x, b4.y, b4.z, b4.w};
            #pragma unroll
            for (int i = 0; i < 4; ++i)
                #pragma unroll
                for (int j = 0; j < 4; ++j)
                    c[i][j] += av[i] * bv[j];
        }
        __syncthreads();
    }
}

// generic: C = act(A@B + bias), row-major store
__global__ __launch_bounds__(256)
void gemm_kernel(const float* __restrict__ A1, const float* __restrict__ A2, int splitK,
                 const float* __restrict__ B, const float* __restrict__ bias,
                 float* __restrict__ C, int Nn, int K, int act) {
    __shared__ float As[16][68];
    __shared__ float Bs[16][68];
    int t  = threadIdx.x;
    int tx = t & 15, ty = t >> 4;
    int i0 = blockIdx.y * 64, j0 = blockIdx.x * 64;
    float c[4][4] = {};
    gemm_tile(A1, A2, splitK, B, Nn, K, i0, j0, t, c, As, Bs);
    #pragma unroll
    for (int i = 0; i < 4; ++i) {
        int row = i0 + ty * 4 + i;
        int col = j0 + tx * 4;
        float4 o;
        float* op = &o.x;
        #pragma unroll
        for (int j = 0; j < 4; ++j) {
            float vv = c[i][j] + (bias ? bias[col + j] : 0.0f);
            if (act == 1) vv = silu_f(vv);
            op[j] = vv;
        }
        *(float4*)&C[row * (long)Nn + col] = o;
    }
}

// fused QKV: z=0 q=src@Wq+bq (normal), z=1 kT=(tgt@Wk+bk)^T, z=2 v=tgt@Wv+bv
__global__ __launch_bounds__(256)
void qkv_kernel(const float* __restrict__ src, const float* __restrict__ tgt,
                const float* __restrict__ Wq, const float* __restrict__ bq,
                const float* __restrict__ Wk, const float* __restrict__ bk,
                const float* __restrict__ Wv, const float* __restrict__ bv,
                float* __restrict__ qb, float* __restrict__ kT, float* __restrict__ vb) {
    __shared__ float As[16][68];
    __shared__ float Bs[16][68];
    int t  = threadIdx.x;
    int tx = t & 15, ty = t >> 4;
    int i0 = blockIdx.y * 64, j0 = blockIdx.x * 64;
    int z = blockIdx.z;
    const float* A  = (z == 0) ? src : tgt;
    const float* B  = (z == 0) ? Wq : (z == 1) ? Wk : Wv;
    const float* bi = (z == 0) ? bq : (z == 1) ? bk : bv;
    float c[4][4] = {};
    gemm_tile(A, A, HIDD, B, HIDD, HIDD, i0, j0, t, c, As, Bs);
    if (z == 1) {
        // transposed store: kT[col][row]
        #pragma unroll
        for (int j = 0; j < 4; ++j) {
            int col = j0 + tx * 4 + j;
            float bb = bi[col];
            float4 o = {c[0][j] + bb, c[1][j] + bb, c[2][j] + bb, c[3][j] + bb};
            *(float4*)&kT[col * NN + i0 + ty * 4] = o;
        }
    } else {
        float* C = (z == 0) ? qb : vb;
        #pragma unroll
        for (int i = 0; i < 4; ++i) {
            int row = i0 + ty * 4 + i;
            int col = j0 + tx * 4;
            float4 o = {c[i][0] + bi[col], c[i][1] + bi[col + 1],
                        c[i][2] + bi[col + 2], c[i][3] + bi[col + 3]};
            *(float4*)&C[row * HIDD + col] = o;
        }
    }
}

// ---------------- gate logits + 2-way softmax (one block per row) ----------------

__global__ __launch_bounds__(256)
void gate_final_kernel(const float* __restrict__ gh, const float* __restrict__ w2,
                       const float* __restrict__ b2, float* __restrict__ gate) {
    __shared__ float w2s[2048];
    __shared__ float red[8];
    int n = blockIdx.x, t = threadIdx.x;
    #pragma unroll
    for (int l = 0; l < 8; ++l) w2s[t + 256 * l] = w2[t + 256 * l];
    __syncthreads();
    float4 x = ((const float4*)(gh + (long)n * 1024))[t];
    float l0 = x.x * w2s[8 * t]     + x.y * w2s[8 * t + 2] +
               x.z * w2s[8 * t + 4] + x.w * w2s[8 * t + 6];
    float l1 = x.x * w2s[8 * t + 1] + x.y * w2s[8 * t + 3] +
               x.z * w2s[8 * t + 5] + x.w * w2s[8 * t + 7];
    #pragma unroll
    for (int off = 32; off > 0; off >>= 1) {
        l0 += __shfl_xor(l0, off, 64);
        l1 += __shfl_xor(l1, off, 64);
    }
    if ((t & 63) == 0) { red[(t >> 6) * 2] = l0; red[(t >> 6) * 2 + 1] = l1; }
    __syncthreads();
    if (t == 0) {
        float L0 = b2[0] + red[0] + red[2] + red[4] + red[6];
        float L1 = b2[1] + red[1] + red[3] + red[5] + red[7];
        float mx = fmaxf(L0, L1);
        float e0 = __expf(L0 - mx), e1 = __expf(L1 - mx);
        float inv = 1.0f / (e0 + e1);
        gate[2 * n]     = e0 * inv;
        gate[2 * n + 1] = e1 * inv;
    }
}

// ---------------- score: S[h][n][m] = qk*scale + g0*geo + g1*topo ----------------
// grid (4 m-chunks, 1024 n); thread t -> m = chunk*256+t (coalesced kT reads)

__global__ __launch_bounds__(256)
void score_kernel(const float* __restrict__ q, const float* __restrict__ kT,
                  const float* __restrict__ pos, const float* __restrict__ gate,
                  const unsigned* __restrict__ pbits, const float* __restrict__ t01,
                  const float* __restrict__ gw1, const float* __restrict__ gb1,
                  const float* __restrict__ gw2, const float* __restrict__ gb2,
                  float* __restrict__ S) {
    __shared__ float qs[HIDD];
    __shared__ float w1s[32], b1s[32], w2s[256], b2s[8], t01s[16];
    __shared__ unsigned prow[NW];
    __shared__ float posn[3];
    int n = blockIdx.y;
    int t = threadIdx.x;
    int m = blockIdx.x * 256 + t;
    qs[t]  = q[n * HIDD + t];
    w2s[t] = gw2[t];
    if (t < 32) { w1s[t] = gw1[t]; b1s[t] = gb1[t]; prow[t] = pbits[n * NW + t]; }
    if (t < 16) t01s[t] = t01[t];
    if (t < 8)  b2s[t] = gb2[t];
    if (t < 3)  posn[t] = pos[n * 3 + t];
    __syncthreads();
    float g0 = gate[2 * n], g1 = gate[2 * n + 1];
    const float scale = 0.17677669529663687f;  // 1/sqrt(32)

    float dx = posn[0] - pos[m * 3];
    float dy = posn[1] - pos[m * 3 + 1];
    float dz = posn[2] - pos[m * 3 + 2];
    float dist = sqrtf(fmaxf(dx * dx + dy * dy + dz * dz, 1e-12f));
    float go[8];
    #pragma unroll
    for (int h = 0; h < 8; ++h) go[h] = b2s[h];
    #pragma unroll 4
    for (int c = 0; c < 32; ++c) {
        float hh = silu_f(dist * w1s[c] + b1s[c]);
        #pragma unroll
        for (int h = 0; h < 8; ++h) go[h] += hh * w2s[c * 8 + h];
    }
    float qk[8] = {0.f, 0.f, 0.f, 0.f, 0.f, 0.f, 0.f, 0.f};
    const float4* q4 = (const float4*)qs;
    #pragma unroll 8
    for (int d4 = 0; d4 < 64; ++d4) {
        float4 qv = q4[d4];
        const float* kp = kT + (d4 * 4) * NN + m;
        qk[d4 >> 3] += qv.x * kp[0] + qv.y * kp[NN] + qv.z * kp[2 * NN] + qv.w * kp[3 * NN];
    }
    unsigned pb = (prow[m >> 5] >> (m & 31)) & 1u;
    #pragma unroll
    for (int h = 0; h < 8; ++h) {
        float tb = pb ? t01s[8 + h] : t01s[h];
        S[((long)h << 20) + n * NN + m] = qk[h] * scale + g0 * go[h] + g1 * tb;
    }
}

// ---------------- softmax + PV, 4 rows per block ----------------
// grid (8 heads, 256 row-groups)

#define RG 4

__global__ __launch_bounds__(256)
void softpv_kernel(const float* __restrict__ S, const float* __restrict__ v,
                   float* __restrict__ out) {
    __shared__ float sr[RG][NN];        // 16 KB
    __shared__ float part[8][RG][32];   // 4 KB
    __shared__ float invs[RG];
    int h  = blockIdx.x;
    int n0 = blockIdx.y * RG;
    int t  = threadIdx.x;
    const float4* S4 = (const float4*)(S + ((long)h << 20) + (long)n0 * NN);
    #pragma unroll
    for (int r = 0; r < RG; ++r)
        ((float4*)sr[r])[t] = S4[r * 256 + t];
    __syncthreads();
    {   // softmax: wave r handles row r
        int r = t >> 6, l = t & 63;
        float mx = -1e30f;
        #pragma unroll 4
        for (int m = l; m < NN; m += 64) mx = fmaxf(mx, sr[r][m]);
        #pragma unroll
        for (int off = 32; off > 0; off >>= 1) mx = fmaxf(mx, __shfl_xor(mx, off, 64));
        float sum = 0.0f;
        #pragma unroll 4
        for (int m = l; m < NN; m += 64) {
            float e = __expf(sr[r][m] - mx);
            sr[r][m] = e;
            sum += e;
        }
        #pragma unroll
        for (int off = 32; off > 0; off >>= 1) sum += __shfl_xor(sum, off, 64);
        if (l == 0) invs[r] = 1.0f / sum;
    }
    __syncthreads();
    {   // PV: thread (chunk, d); 128 m per chunk, v load shared across RG rows
        int dd = t & 31, ch = t >> 5;
        float acc[RG] = {};
        const float* vp = v + (ch * 128) * HIDD + h * 32 + dd;
        #pragma unroll 4
        for (int i = 0; i < 128; ++i) {
            float vv = vp[i * HIDD];
            int m = ch * 128 + i;
            #pragma unroll
            for (int r = 0; r < RG; ++r) acc[r] += sr[r][m] * vv;
        }
        #pragma unroll
        for (int r = 0; r < RG; ++r) part[ch][r][dd] = acc[r];
    }
    __syncthreads();
    if (t < RG * 32) {
        int r = t >> 5, d2 = t & 31;
        float s = 0.0f;
        #pragma unroll
        for (int c = 0; c < 8; ++c) s += part[c][r][d2];
        out[(n0 + r) * HIDD + h * 32 + d2] = s * invs[r];
    }
}

// ---------------- residual + LayerNorm ----------------

__global__ __launch_bounds__(256)
void ln_kernel(const float* __restrict__ xres, const float* __restrict__ proj,
               const float* __restrict__ g, const float* __restrict__ b,
               float* __restrict__ out) {
    __shared__ float red[8];
    int n = blockIdx.x, t = threadIdx.x;
    float x = xres[n * HIDD + t] + proj[n * HIDD + t];
    float sg = x;
    #pragma unroll
    for (int off = 32; off > 0; off >>= 1) sg += __shfl_down(sg, off, 64);
    int wid = t >> 6;
    if ((t & 63) == 0) red[wid] = sg;
    __syncthreads();
    float mean = (red[0] + red[1] + red[2] + red[3]) * (1.0f / HIDD);
    float dx = x - mean;
    float s2 = dx * dx;
    #pragma unroll
    for (int off = 32; off > 0; off >>= 1) s2 += __shfl_down(s2, off, 64);
    if ((t & 63) == 0) red[4 + wid] = s2;
    __syncthreads();
    float var = (red[4] + red[5] + red[6] + red[7]) * (1.0f / HIDD);
    out[n * HIDD + t] = dx * rsqrtf(var + 1e-5f) * g[t] + b[t];
}

// ---------------- host ----------------

extern "C" void kernel_launch(void* const* d_in, const int* in_sizes, int n_in,
                              void* d_out, int out_size, void* d_ws, size_t ws_size,
                              hipStream_t stream) {
    const float* src  = (const float*)d_in[0];
    const float* tgt  = (const float*)d_in[1];
    const float* pos  = (const float*)d_in[2];
    const int*   ei   = (const int*)d_in[3];
    const float* Wq   = (const float*)d_in[4];  const float* bq  = (const float*)d_in[5];
    const float* Wk   = (const float*)d_in[6];  const float* bk  = (const float*)d_in[7];
    const float* Wv   = (const float*)d_in[8];  const float* bv  = (const float*)d_in[9];
    const float* gw1  = (const float*)d_in[10]; const float* gb1 = (const float*)d_in[11];
    const float* gw2  = (const float*)d_in[12]; const float* gb2 = (const float*)d_in[13];
    const float* tw1  = (const float*)d_in[14]; const float* tb1 = (const float*)d_in[15];
    const float* tw2  = (const float*)d_in[16]; const float* tb2 = (const float*)d_in[17];
    const float* gaw1 = (const float*)d_in[18]; const float* gab1= (const float*)d_in[19];
    const float* gaw2 = (const float*)d_in[20]; const float* gab2= (const float*)d_in[21];
    const float* Wo   = (const float*)d_in[22]; const float* bo  = (const float*)d_in[23];
    const float* lng  = (const float*)d_in[24]; const float* lnb = (const float*)d_in[25];
    int E = in_sizes[3] / 2;

    char* w = (char*)d_ws;
    unsigned* acol = (unsigned*)w; w += NN * NW * 4;      // 128 KB
    unsigned* p0   = (unsigned*)w; w += NN * NW * 4;      // 128 KB (contiguous with acol)
    unsigned* p1   = (unsigned*)w; w += NN * NW * 4;
    float* qb   = (float*)w; w += NN * HIDD * 4;
    float* kT   = (float*)w; w += NN * HIDD * 4;          // [256][1024] transposed
    float* vb   = (float*)w; w += NN * HIDD * 4;
    float* gh   = (float*)w; w += (long)NN * 1024 * 4;    // 4 MB
    float* gate = (float*)w; w += NN * 2 * 4;
    float* t01  = (float*)w; w += 256;
    float* aout = (float*)w; w += NN * HIDD * 4;
    float* pout = (float*)w; w += NN * HIDD * 4;
    float* S    = (float*)w; w += (long)NH * NN * NN * 4; // 32 MB

    // adjacency bits (acol + p0 contiguous -> one memset)
    hipMemsetAsync(acol, 0, 2 * NN * NW * 4, stream);
    scatter_edges_kernel<<<(E + 255) / 256, 256, 0, stream>>>(ei, E, p0, acol);
    path_iter_kernel<<<NN / 8, 256, 0, stream>>>(p0, acol, p1);
    path_iter_kernel<<<NN / 8, 256, 0, stream>>>(p1, acol, p0);
    path_iter_kernel<<<NN / 8, 256, 0, stream>>>(p0, acol, p1);   // final path in p1
    topo_t01_kernel<<<1, 64, 0, stream>>>(tw1, tb1, tw2, tb2, t01);

    // QKV fused (k transposed)
    dim3 gQKV(HIDD / 64, NN / 64, 3);
    qkv_kernel<<<gQKV, 256, 0, stream>>>(src, tgt, Wq, bq, Wk, bk, Wv, bv, qb, kT, vb);

    // gate MLP
    dim3 gG(1024 / 64, NN / 64);
    gemm_kernel<<<gG, 256, 0, stream>>>(src, tgt, HIDD, gaw1, gab1, gh, 1024, 512, 1);
    gate_final_kernel<<<NN, 256, 0, stream>>>(gh, gaw2, gab2, gate);

    // scores -> softmax+PV
    dim3 gS(4, NN);
    score_kernel<<<gS, 256, 0, stream>>>(qb, kT, pos, gate, p1, t01,
                                         gw1, gb1, gw2, gb2, S);
    dim3 gP(NH, NN / RG);
    softpv_kernel<<<gP, 256, 0, stream>>>(S, vb, aout);

    // output projection + LN
    dim3 gO(HIDD / 64, NN / 64);
    gemm_kernel<<<gO, 256, 0, stream>>>(aout, aout, HIDD, Wo, bo, pout, HIDD, HIDD, 0);
    ln_kernel<<<NN, 256, 0, stream>>>(src, pout, lng, lnb, (float*)d_out);
}

// Round 3
// 321.723 us; speedup vs baseline: 2.1586x; 1.1541x over previous
//
#include <hip/hip_runtime.h>
#include <math.h>

#define NN   1024
#define HIDD 256
#define NH   8
#define NW   32   // 1024 bits / 32 per word

typedef __attribute__((ext_vector_type(8))) short short8;
typedef __attribute__((ext_vector_type(4))) float f32x4;

__device__ __forceinline__ float silu_f(float x) {
    return x / (1.0f + __expf(-x));
}
__device__ __forceinline__ unsigned short f2bf(float x) {
    unsigned b = __float_as_uint(x);
    return (unsigned short)((b + 0x7FFFu + ((b >> 16) & 1u)) >> 16);
}
__device__ __forceinline__ float bf2f(unsigned short u) {
    return __uint_as_float(((unsigned)u) << 16);
}

// ---------------- path propagation (bit-packed boolean) ----------------

__global__ void scatter_edges_kernel(const int* __restrict__ ei, int E,
                                     unsigned* __restrict__ prow,
                                     unsigned* __restrict__ acol) {
    int e = blockIdx.x * 256 + threadIdx.x;
    if (e >= E) return;
    int r = ei[e], c = ei[E + e];
    if ((unsigned)r < NN && (unsigned)c < NN) {
        atomicOr(&prow[r * NW + (c >> 5)], 1u << (c & 31));
        atomicOr(&acol[c * NW + (r >> 5)], 1u << (r & 31));
    }
}

__global__ __launch_bounds__(256)
void path_iter_kernel(const unsigned* __restrict__ pin,
                      const unsigned* __restrict__ acol,
                      unsigned* __restrict__ pout) {
    __shared__ unsigned pr[8][NW];
    int t  = threadIdx.x;
    int ty = t >> 5;
    int wj = t & 31;
    int i  = blockIdx.x * 8 + ty;
    pr[ty][wj] = pin[i * NW + wj];
    __syncthreads();
    unsigned inw  = pr[ty][wj];
    unsigned outw = 0u;
    for (int b = 0; b < 32; ++b) {
        int j = (wj << 5) | b;
        const unsigned* ac = &acol[j * NW];
        unsigned acc = 0u;
        #pragma unroll
        for (int w = 0; w < NW; ++w) acc |= pr[ty][w] & ac[w];
        outw |= (acc ? 1u : 0u) << b;
    }
    pout[i * NW + wj] = inw & outw;
}

__global__ void topo_t01_kernel(const float* __restrict__ w1, const float* __restrict__ b1,
                                const float* __restrict__ w2, const float* __restrict__ b2,
                                float* __restrict__ t01) {
    int t = threadIdx.x;
    if (t >= 16) return;
    int h = t & 7;
    float x = (t >> 3) ? 1.0f : 0.0f;
    float acc = b2[h];
    for (int c = 0; c < 32; ++c)
        acc += silu_f(x * w1[c] + b1[c]) * w2[c * 8 + h];
    t01[t] = acc;
}

// ---------------- fp32 -> bf16 conversions ----------------

// src/tgt -> bf16 copies + concat [src|tgt] for the gate GEMM A
__global__ __launch_bounds__(256)
void convert_acts_kernel(const float* __restrict__ src, const float* __restrict__ tgt,
                         unsigned short* __restrict__ src_bf,
                         unsigned short* __restrict__ tgt_bf,
                         unsigned short* __restrict__ gateA) {
    int idx = blockIdx.x * 256 + threadIdx.x;    // 1024*512 total
    int n = idx >> 9, j = idx & 511;
    if (j < 256) {
        unsigned short u = f2bf(src[n * 256 + j]);
        src_bf[n * 256 + j] = u;
        gateA[n * 512 + j]  = u;
    } else {
        int jj = j - 256;
        unsigned short u = f2bf(tgt[n * 256 + jj]);
        tgt_bf[n * 256 + jj] = u;
        gateA[n * 512 + j]   = u;
    }
}

// W [Kd][Nd] fp32 -> Wt [Nd][Kd] bf16
__global__ __launch_bounds__(256)
void transpose_bf16_kernel(const float* __restrict__ W, unsigned short* __restrict__ Wt,
                           int Kd, int Nd) {
    __shared__ float tile[32][33];
    int t = threadIdx.x, tx = t & 31, ty = t >> 5;
    int n0 = blockIdx.x * 32, k0 = blockIdx.y * 32;
    #pragma unroll
    for (int p = 0; p < 4; ++p)
        tile[ty + p * 8][tx] = W[(k0 + ty + p * 8) * (long)Nd + n0 + tx];
    __syncthreads();
    #pragma unroll
    for (int p = 0; p < 4; ++p)
        Wt[(n0 + ty + p * 8) * (long)Kd + k0 + tx] = f2bf(tile[tx][ty + p * 8]);
}

// ---------------- shared MFMA 64x64 tile ----------------
// A [M][K] bf16 row-major, Bt [N][K] bf16 row-major (B pre-transposed).
// 256 threads = 4 waves, wave (wi,wj) owns a 32x32 quadrant = 2x2 mfma tiles.
// Verified layouts: A[m=lane&15][k=quad*8+j]; B[k=quad*8+j][n=lane&15];
// C/D: col=lane&15, row=quad*4+reg.

__device__ __forceinline__ void mfma_tile64(const unsigned short* __restrict__ A,
                                            const unsigned short* __restrict__ Bt,
                                            int K, int i0, int j0, int t,
                                            f32x4 acc[2][2],
                                            unsigned short* As, unsigned short* Bs) {
    int l = t & 63, w = t >> 6;
    int wi = w >> 1, wj = w & 1;
    int quad = l >> 4, lj = l & 15;
    int sr = t >> 2, skp = (t & 3) * 8;
    f32x4 z = {0.f, 0.f, 0.f, 0.f};
    acc[0][0] = z; acc[0][1] = z; acc[1][0] = z; acc[1][1] = z;
    for (int k0 = 0; k0 < K; k0 += 32) {
        *(int4*)&As[sr * 32 + skp] = *(const int4*)&A[(i0 + sr) * (long)K + k0 + skp];
        *(int4*)&Bs[sr * 32 + skp] = *(const int4*)&Bt[(j0 + sr) * (long)K + k0 + skp];
        __syncthreads();
        short8 a0 = *(short8*)&As[(wi * 32 + lj) * 32 + quad * 8];
        short8 a1 = *(short8*)&As[(wi * 32 + 16 + lj) * 32 + quad * 8];
        short8 b0 = *(short8*)&Bs[(wj * 32 + lj) * 32 + quad * 8];
        short8 b1 = *(short8*)&Bs[(wj * 32 + 16 + lj) * 32 + quad * 8];
        acc[0][0] = __builtin_amdgcn_mfma_f32_16x16x32_bf16(a0, b0, acc[0][0], 0, 0, 0);
        acc[0][1] = __builtin_amdgcn_mfma_f32_16x16x32_bf16(a0, b1, acc[0][1], 0, 0, 0);
        acc[1][0] = __builtin_amdgcn_mfma_f32_16x16x32_bf16(a1, b0, acc[1][0], 0, 0, 0);
        acc[1][1] = __builtin_amdgcn_mfma_f32_16x16x32_bf16(a1, b1, acc[1][1], 0, 0, 0);
        __syncthreads();
    }
}

// mode 0: fp32 = x+bias; mode 1: fp32 = silu(x+bias); mode 2: bf16 = x+bias
__global__ __launch_bounds__(256)
void gemm_bf16_kernel(const unsigned short* __restrict__ A,
                      const unsigned short* __restrict__ Bt,
                      const float* __restrict__ bias,
                      void* __restrict__ Cout, int M, int N, int K, int mode) {
    __shared__ unsigned short As[64 * 32];
    __shared__ unsigned short Bs[64 * 32];
    int t = threadIdx.x;
    int i0 = blockIdx.y * 64, j0 = blockIdx.x * 64;
    f32x4 acc[2][2];
    mfma_tile64(A, Bt, K, i0, j0, t, acc, As, Bs);
    int l = t & 63, w = t >> 6, wi = w >> 1, wj = w & 1, quad = l >> 4, lj = l & 15;
    #pragma unroll
    for (int rg = 0; rg < 2; ++rg)
        #pragma unroll
        for (int cg = 0; cg < 2; ++cg) {
            int col  = j0 + wj * 32 + cg * 16 + lj;
            int row0 = i0 + wi * 32 + rg * 16 + quad * 4;
            float bb = bias ? bias[col] : 0.0f;
            #pragma unroll
            for (int r = 0; r < 4; ++r) {
                float v = acc[rg][cg][r] + bb;
                if (mode == 1) v = silu_f(v);
                if (mode == 2) ((unsigned short*)Cout)[(row0 + r) * (long)N + col] = f2bf(v);
                else           ((float*)Cout)[(row0 + r) * (long)N + col] = v;
            }
        }
}

// z=0: q_bf = src@Wq+bq (bf16); z=1: k_bf (bf16); z=2: v fp32
__global__ __launch_bounds__(256)
void qkv_kernel(const unsigned short* __restrict__ src_bf,
                const unsigned short* __restrict__ tgt_bf,
                const unsigned short* __restrict__ WqT,
                const unsigned short* __restrict__ WkT,
                const unsigned short* __restrict__ WvT,
                const float* __restrict__ bq, const float* __restrict__ bk,
                const float* __restrict__ bv,
                unsigned short* __restrict__ q_bf, unsigned short* __restrict__ k_bf,
                float* __restrict__ v_f) {
    __shared__ unsigned short As[64 * 32];
    __shared__ unsigned short Bs[64 * 32];
    int t = threadIdx.x;
    int z = blockIdx.z;
    int i0 = blockIdx.y * 64, j0 = blockIdx.x * 64;
    const unsigned short* A  = (z == 0) ? src_bf : tgt_bf;
    const unsigned short* Bt = (z == 0) ? WqT : (z == 1) ? WkT : WvT;
    const float* bias        = (z == 0) ? bq : (z == 1) ? bk : bv;
    f32x4 acc[2][2];
    mfma_tile64(A, Bt, HIDD, i0, j0, t, acc, As, Bs);
    int l = t & 63, w = t >> 6, wi = w >> 1, wj = w & 1, quad = l >> 4, lj = l & 15;
    unsigned short* obf = (z == 0) ? q_bf : k_bf;
    #pragma unroll
    for (int rg = 0; rg < 2; ++rg)
        #pragma unroll
        for (int cg = 0; cg < 2; ++cg) {
            int col  = j0 + wj * 32 + cg * 16 + lj;
            int row0 = i0 + wi * 32 + rg * 16 + quad * 4;
            float bb = bias[col];
            #pragma unroll
            for (int r = 0; r < 4; ++r) {
                float v = acc[rg][cg][r] + bb;
                if (z < 2) obf[(row0 + r) * HIDD + col] = f2bf(v);
                else       v_f[(row0 + r) * HIDD + col] = v;
            }
        }
}

// ---------------- gate logits + 2-way softmax ----------------

__global__ __launch_bounds__(256)
void gate_final_kernel(const float* __restrict__ gh, const float* __restrict__ w2,
                       const float* __restrict__ b2, float* __restrict__ gate) {
    __shared__ float w2s[2048];
    __shared__ float red[8];
    int n = blockIdx.x, t = threadIdx.x;
    #pragma unroll
    for (int l = 0; l < 8; ++l) w2s[t + 256 * l] = w2[t + 256 * l];
    __syncthreads();
    float4 x = ((const float4*)(gh + (long)n * 1024))[t];
    float l0 = x.x * w2s[8 * t]     + x.y * w2s[8 * t + 2] +
               x.z * w2s[8 * t + 4] + x.w * w2s[8 * t + 6];
    float l1 = x.x * w2s[8 * t + 1] + x.y * w2s[8 * t + 3] +
               x.z * w2s[8 * t + 5] + x.w * w2s[8 * t + 7];
    #pragma unroll
    for (int off = 32; off > 0; off >>= 1) {
        l0 += __shfl_xor(l0, off, 64);
        l1 += __shfl_xor(l1, off, 64);
    }
    if ((t & 63) == 0) { red[(t >> 6) * 2] = l0; red[(t >> 6) * 2 + 1] = l1; }
    __syncthreads();
    if (t == 0) {
        float L0 = b2[0] + red[0] + red[2] + red[4] + red[6];
        float L1 = b2[1] + red[1] + red[3] + red[5] + red[7];
        float mx = fmaxf(L0, L1);
        float e0 = __expf(L0 - mx), e1 = __expf(L1 - mx);
        float inv = 1.0f / (e0 + e1);
        gate[2 * n]     = e0 * inv;
        gate[2 * n + 1] = e1 * inv;
    }
}

// ---------------- score via MFMA: 64x64 pair blocks, all 8 heads ----------------
// phase 1: per-pair geo MLP -> LDS bf16 table (computed once per pair)
// phase 2: per head, QK^T via 16x16x32 MFMA reading q_bf/k_bf from global,
//          epilogue adds gated geo/topo bias, stores S[h][n][m] fp32.

__global__ __launch_bounds__(256)
void score_mfma_kernel(const unsigned short* __restrict__ qbf,
                       const unsigned short* __restrict__ kbf,
                       const float* __restrict__ pos, const float* __restrict__ gate,
                       const unsigned* __restrict__ pbits, const float* __restrict__ t01,
                       const float* __restrict__ gw1, const float* __restrict__ gb1,
                       const float* __restrict__ gw2, const float* __restrict__ gb2,
                       float* __restrict__ S) {
    __shared__ unsigned short geo[4096 * 8];   // 64 KB  [pair][h]
    __shared__ float posA[192], posB[192];
    __shared__ unsigned prowL[128];            // [i][word]
    __shared__ float g01[128];
    __shared__ float w1s[32], b1s[32], w2s[256], b2s[8], t01s[16];
    int t  = threadIdx.x;
    int n0 = blockIdx.y * 64, m0 = blockIdx.x * 64;
    w2s[t] = gw2[t];
    if (t < 192) { posA[t] = pos[n0 * 3 + t]; posB[t] = pos[m0 * 3 + t]; }
    if (t < 128) {
        prowL[t] = pbits[(n0 + (t >> 1)) * NW + (m0 >> 5) + (t & 1)];
        g01[t]   = gate[n0 * 2 + t];
    }
    if (t < 32) { w1s[t] = gw1[t]; b1s[t] = gb1[t]; }
    if (t < 16) t01s[t] = t01[t];
    if (t < 8)  b2s[t] = b2s[t] = gb2[t];
    __syncthreads();

    // phase 1: 16 pairs per thread (thread-interleaved for conflict-free writes)
    for (int pp = 0; pp < 16; ++pp) {
        int p = pp * 256 + t;
        int i = p >> 6, j = p & 63;
        float dx = posA[i * 3]     - posB[j * 3];
        float dy = posA[i * 3 + 1] - posB[j * 3 + 1];
        float dz = posA[i * 3 + 2] - posB[j * 3 + 2];
        float dist = sqrtf(fmaxf(dx * dx + dy * dy + dz * dz, 1e-12f));
        float go[8];
        #pragma unroll
        for (int h = 0; h < 8; ++h) go[h] = b2s[h];
        #pragma unroll 4
        for (int c = 0; c < 32; ++c) {
            float hh = silu_f(dist * w1s[c] + b1s[c]);
            #pragma unroll
            for (int h = 0; h < 8; ++h) go[h] += hh * w2s[c * 8 + h];
        }
        short8 packed;
        #pragma unroll
        for (int h = 0; h < 8; ++h) packed[h] = (short)f2bf(go[h]);
        *(short8*)&geo[p * 8] = packed;
    }
    __syncthreads();

    // phase 2: wave w owns local rows [w*16, w*16+16), all cols, all heads
    int l = t & 63, w = t >> 6, quad = l >> 4, lj = l & 15;
    const float scale = 0.17677669529663687f;  // 1/sqrt(32)
    for (int h = 0; h < 8; ++h) {
        short8 a = *(const short8*)&qbf[(n0 + w * 16 + lj) * HIDD + h * 32 + quad * 8];
        f32x4 z = {0.f, 0.f, 0.f, 0.f};
        f32x4 acc[4];
        #pragma unroll
        for (int cg = 0; cg < 4; ++cg) {
            short8 b = *(const short8*)&kbf[(m0 + cg * 16 + lj) * HIDD + h * 32 + quad * 8];
            acc[cg] = __builtin_amdgcn_mfma_f32_16x16x32_bf16(a, b, z, 0, 0, 0);
        }
        #pragma unroll
        for (int cg = 0; cg < 4; ++cg) {
            int j = cg * 16 + lj;
            #pragma unroll
            for (int r = 0; r < 4; ++r) {
                int i = w * 16 + quad * 4 + r;
                float geo_v = bf2f(geo[(i * 64 + j) * 8 + h]);
                unsigned bit = (prowL[i * 2 + (j >> 5)] >> (j & 31)) & 1u;
                float val = acc[cg][r] * scale + g01[i * 2] * geo_v +
                            g01[i * 2 + 1] * t01s[bit * 8 + h];
                S[((long)h << 20) + (n0 + i) * NN + m0 + j] = val;
            }
        }
    }
}

// ---------------- softmax + PV, 8 rows per block; bf16 output ----------------

#define RG 8

__global__ __launch_bounds__(256)
void softpv_kernel(const float* __restrict__ S, const float* __restrict__ v,
                   unsigned short* __restrict__ out_bf) {
    __shared__ float sr[RG][NN];        // 32 KB
    __shared__ float part[8][RG][32];   // 8 KB
    __shared__ float invs[RG];
    int h  = blockIdx.x;
    int n0 = blockIdx.y * RG;
    int t  = threadIdx.x;
    const float4* S4 = (const float4*)(S + ((long)h << 20) + (long)n0 * NN);
    #pragma unroll
    for (int r = 0; r < RG; ++r)
        ((float4*)sr[r])[t] = S4[r * 256 + t];
    __syncthreads();
    {   // softmax: wave wv handles rows wv and wv+4
        int wv = t >> 6, l = t & 63;
        #pragma unroll
        for (int rr = 0; rr < 2; ++rr) {
            int r = wv + rr * 4;
            float mx = -1e30f;
            #pragma unroll 4
            for (int m = l; m < NN; m += 64) mx = fmaxf(mx, sr[r][m]);
            #pragma unroll
            for (int off = 32; off > 0; off >>= 1) mx = fmaxf(mx, __shfl_xor(mx, off, 64));
            float sum = 0.0f;
            #pragma unroll 4
            for (int m = l; m < NN; m += 64) {
                float e = __expf(sr[r][m] - mx);
                sr[r][m] = e;
                sum += e;
            }
            #pragma unroll
            for (int off = 32; off > 0; off >>= 1) sum += __shfl_xor(sum, off, 64);
            if (l == 0) invs[r] = 1.0f / sum;
        }
    }
    __syncthreads();
    {   // PV: thread (chunk, d); 128 m per chunk, v load shared across RG rows
        int dd = t & 31, ch = t >> 5;
        float acc[RG] = {};
        const float* vp = v + (ch * 128) * HIDD + h * 32 + dd;
        #pragma unroll 4
        for (int i = 0; i < 128; ++i) {
            float vv = vp[i * HIDD];
            int m = ch * 128 + i;
            #pragma unroll
            for (int r = 0; r < RG; ++r) acc[r] += sr[r][m] * vv;
        }
        #pragma unroll
        for (int r = 0; r < RG; ++r) part[ch][r][dd] = acc[r];
    }
    __syncthreads();
    {
        int r = t >> 5, d2 = t & 31;
        float s = 0.0f;
        #pragma unroll
        for (int c = 0; c < 8; ++c) s += part[c][r][d2];
        out_bf[(n0 + r) * HIDD + h * 32 + d2] = f2bf(s * invs[r]);
    }
}

// ---------------- residual + LayerNorm ----------------

__global__ __launch_bounds__(256)
void ln_kernel(const float* __restrict__ xres, const float* __restrict__ proj,
               const float* __restrict__ g, const float* __restrict__ b,
               float* __restrict__ out) {
    __shared__ float red[8];
    int n = blockIdx.x, t = threadIdx.x;
    float x = xres[n * HIDD + t] + proj[n * HIDD + t];
    float sg = x;
    #pragma unroll
    for (int off = 32; off > 0; off >>= 1) sg += __shfl_down(sg, off, 64);
    int wid = t >> 6;
    if ((t & 63) == 0) red[wid] = sg;
    __syncthreads();
    float mean = (red[0] + red[1] + red[2] + red[3]) * (1.0f / HIDD);
    float dx = x - mean;
    float s2 = dx * dx;
    #pragma unroll
    for (int off = 32; off > 0; off >>= 1) s2 += __shfl_down(s2, off, 64);
    if ((t & 63) == 0) red[4 + wid] = s2;
    __syncthreads();
    float var = (red[4] + red[5] + red[6] + red[7]) * (1.0f / HIDD);
    out[n * HIDD + t] = dx * rsqrtf(var + 1e-5f) * g[t] + b[t];
}

// ---------------- host ----------------

extern "C" void kernel_launch(void* const* d_in, const int* in_sizes, int n_in,
                              void* d_out, int out_size, void* d_ws, size_t ws_size,
                              hipStream_t stream) {
    const float* src  = (const float*)d_in[0];
    const float* tgt  = (const float*)d_in[1];
    const float* pos  = (const float*)d_in[2];
    const int*   ei   = (const int*)d_in[3];
    const float* Wq   = (const float*)d_in[4];  const float* bq  = (const float*)d_in[5];
    const float* Wk   = (const float*)d_in[6];  const float* bk  = (const float*)d_in[7];
    const float* Wv   = (const float*)d_in[8];  const float* bv  = (const float*)d_in[9];
    const float* gw1  = (const float*)d_in[10]; const float* gb1 = (const float*)d_in[11];
    const float* gw2  = (const float*)d_in[12]; const float* gb2 = (const float*)d_in[13];
    const float* tw1  = (const float*)d_in[14]; const float* tb1 = (const float*)d_in[15];
    const float* tw2  = (const float*)d_in[16]; const float* tb2 = (const float*)d_in[17];
    const float* gaw1 = (const float*)d_in[18]; const float* gab1= (const float*)d_in[19];
    const float* gaw2 = (const float*)d_in[20]; const float* gab2= (const float*)d_in[21];
    const float* Wo   = (const float*)d_in[22]; const float* bo  = (const float*)d_in[23];
    const float* lng  = (const float*)d_in[24]; const float* lnb = (const float*)d_in[25];
    int E = in_sizes[3] / 2;

    char* w = (char*)d_ws;
    unsigned* acol = (unsigned*)w; w += NN * NW * 4;
    unsigned* p0   = (unsigned*)w; w += NN * NW * 4;   // contiguous with acol
    unsigned* p1   = (unsigned*)w; w += NN * NW * 4;
    unsigned short* src_bf = (unsigned short*)w; w += NN * HIDD * 2;
    unsigned short* tgt_bf = (unsigned short*)w; w += NN * HIDD * 2;
    unsigned short* gateA  = (unsigned short*)w; w += NN * 512 * 2;
    unsigned short* WqT    = (unsigned short*)w; w += HIDD * HIDD * 2;
    unsigned short* WkT    = (unsigned short*)w; w += HIDD * HIDD * 2;
    unsigned short* WvT    = (unsigned short*)w; w += HIDD * HIDD * 2;
    unsigned short* WoT    = (unsigned short*)w; w += HIDD * HIDD * 2;
    unsigned short* gaw1T  = (unsigned short*)w; w += 1024 * 512 * 2;
    unsigned short* q_bf   = (unsigned short*)w; w += NN * HIDD * 2;
    unsigned short* k_bf   = (unsigned short*)w; w += NN * HIDD * 2;
    float* v_f  = (float*)w; w += NN * HIDD * 4;
    float* gh   = (float*)w; w += (long)NN * 1024 * 4;  // 4 MB
    float* gate = (float*)w; w += NN * 2 * 4;
    float* t01  = (float*)w; w += 256;
    unsigned short* aout_bf = (unsigned short*)w; w += NN * HIDD * 2;
    float* pout = (float*)w; w += NN * HIDD * 4;
    float* S    = (float*)w; w += (long)NH * NN * NN * 4;  // 32 MB

    // adjacency bits
    hipMemsetAsync(acol, 0, 2 * NN * NW * 4, stream);
    scatter_edges_kernel<<<(E + 255) / 256, 256, 0, stream>>>(ei, E, p0, acol);
    path_iter_kernel<<<NN / 8, 256, 0, stream>>>(p0, acol, p1);
    path_iter_kernel<<<NN / 8, 256, 0, stream>>>(p1, acol, p0);
    path_iter_kernel<<<NN / 8, 256, 0, stream>>>(p0, acol, p1);   // final path in p1
    topo_t01_kernel<<<1, 64, 0, stream>>>(tw1, tb1, tw2, tb2, t01);

    // bf16 conversions
    convert_acts_kernel<<<(NN * 512) / 256, 256, 0, stream>>>(src, tgt, src_bf, tgt_bf, gateA);
    transpose_bf16_kernel<<<dim3(8, 8), 256, 0, stream>>>(Wq, WqT, 256, 256);
    transpose_bf16_kernel<<<dim3(8, 8), 256, 0, stream>>>(Wk, WkT, 256, 256);
    transpose_bf16_kernel<<<dim3(8, 8), 256, 0, stream>>>(Wv, WvT, 256, 256);
    transpose_bf16_kernel<<<dim3(8, 8), 256, 0, stream>>>(Wo, WoT, 256, 256);
    transpose_bf16_kernel<<<dim3(32, 16), 256, 0, stream>>>(gaw1, gaw1T, 512, 1024);

    // QKV (MFMA)
    qkv_kernel<<<dim3(HIDD / 64, NN / 64, 3), 256, 0, stream>>>(
        src_bf, tgt_bf, WqT, WkT, WvT, bq, bk, bv, q_bf, k_bf, v_f);

    // gate MLP (MFMA) + logits/softmax
    gemm_bf16_kernel<<<dim3(16, 16), 256, 0, stream>>>(gateA, gaw1T, gab1, gh,
                                                       1024, 1024, 512, 1);
    gate_final_kernel<<<NN, 256, 0, stream>>>(gh, gaw2, gab2, gate);

    // scores (MFMA + fused bias) -> softmax+PV
    score_mfma_kernel<<<dim3(16, 16), 256, 0, stream>>>(q_bf, k_bf, pos, gate, p1, t01,
                                                        gw1, gb1, gw2, gb2, S);
    softpv_kernel<<<dim3(NH, NN / RG), 256, 0, stream>>>(S, v_f, aout_bf);

    // output projection (MFMA) + LN
    gemm_bf16_kernel<<<dim3(HIDD / 64, NN / 64), 256, 0, stream>>>(
        aout_bf, WoT, bo, pout, 1024, HIDD, HIDD, 0);
    ln_kernel<<<NN, 256, 0, stream>>>(src, pout, lng, lnb, (float*)d_out);
}

// Round 4
// 305.667 us; speedup vs baseline: 2.2720x; 1.0525x over previous
//
#include <hip/hip_runtime.h>
#include <math.h>

#define NN   1024
#define HIDD 256
#define NH   8
#define NW   32   // 1024 bits / 32 per word

typedef __attribute__((ext_vector_type(8))) short short8;
typedef __attribute__((ext_vector_type(4))) float f32x4;

__device__ __forceinline__ float silu_f(float x) {
    return x / (1.0f + __expf(-x));
}
__device__ __forceinline__ unsigned short f2bf(float x) {
    unsigned b = __float_as_uint(x);
    return (unsigned short)((b + 0x7FFFu + ((b >> 16) & 1u)) >> 16);
}
__device__ __forceinline__ float bf2f(unsigned u) {
    return __uint_as_float(u << 16);
}

// ---------------- path propagation (bit-packed boolean) ----------------

__global__ void scatter_edges_kernel(const int* __restrict__ ei, int E,
                                     unsigned* __restrict__ prow,
                                     unsigned* __restrict__ acol) {
    int e = blockIdx.x * 256 + threadIdx.x;
    if (e >= E) return;
    int r = ei[e], c = ei[E + e];
    if ((unsigned)r < NN && (unsigned)c < NN) {
        atomicOr(&prow[r * NW + (c >> 5)], 1u << (c & 31));
        atomicOr(&acol[c * NW + (r >> 5)], 1u << (r & 31));
    }
}

// out[i,j] = in[i,j] & (OR_k in[i,k] & adj[k,j]); row in VGPRs, acol via dwordx4
__global__ __launch_bounds__(256)
void path_iter_kernel(const unsigned* __restrict__ pin,
                      const unsigned* __restrict__ acol,
                      unsigned* __restrict__ pout) {
    int t  = threadIdx.x;
    int ty = t >> 5;     // local row 0..7
    int wj = t & 31;     // output word index
    int i  = blockIdx.x * 8 + ty;
    uint4 pr[8];
    const uint4* prow4 = (const uint4*)&pin[i * NW];
    #pragma unroll
    for (int p = 0; p < 8; ++p) pr[p] = prow4[p];
    unsigned inw  = pin[i * NW + wj];
    unsigned outw = 0u;
    for (int b = 0; b < 32; ++b) {
        int j = (wj << 5) | b;
        const uint4* ac4 = (const uint4*)&acol[j * NW];
        unsigned x0 = 0, x1 = 0, x2 = 0, x3 = 0;
        #pragma unroll
        for (int p = 0; p < 8; ++p) {
            uint4 a = ac4[p];
            x0 |= pr[p].x & a.x;
            x1 |= pr[p].y & a.y;
            x2 |= pr[p].z & a.z;
            x3 |= pr[p].w & a.w;
        }
        unsigned acc = (x0 | x1) | (x2 | x3);
        outw |= (acc ? 1u : 0u) << b;
    }
    pout[i * NW + wj] = inw & outw;
}

// ---------------- fused prep: bf16 converts + weight transposes + topo MLP ----
// blocks [0,2048): convert src/tgt -> src_bf/tgt_bf/gateA
// blocks [2048,2304): transpose Wq/Wk/Wv/Wo (64 tiles each)
// blocks [2304,2816): transpose gaw1 (512x1024)
// block  2816: topo t01

__global__ __launch_bounds__(256)
void prep_kernel(const float* __restrict__ src, const float* __restrict__ tgt,
                 const float* __restrict__ Wq, const float* __restrict__ Wk,
                 const float* __restrict__ Wv, const float* __restrict__ Wo,
                 const float* __restrict__ gaw1,
                 const float* __restrict__ tw1, const float* __restrict__ tb1,
                 const float* __restrict__ tw2, const float* __restrict__ tb2,
                 unsigned short* __restrict__ src_bf, unsigned short* __restrict__ tgt_bf,
                 unsigned short* __restrict__ gateA,
                 unsigned short* __restrict__ WqT, unsigned short* __restrict__ WkT,
                 unsigned short* __restrict__ WvT, unsigned short* __restrict__ WoT,
                 unsigned short* __restrict__ gaw1T,
                 float* __restrict__ t01) {
    __shared__ float tile[32][33];
    int b = blockIdx.x, t = threadIdx.x;
    if (b < 2048) {
        int idx = b * 256 + t;
        int n = idx >> 9, j = idx & 511;
        if (j < 256) {
            unsigned short u = f2bf(src[n * 256 + j]);
            src_bf[n * 256 + j] = u;
            gateA[n * 512 + j]  = u;
        } else {
            int jj = j - 256;
            unsigned short u = f2bf(tgt[n * 256 + jj]);
            tgt_bf[n * 256 + jj] = u;
            gateA[n * 512 + j]   = u;
        }
    } else if (b < 2816) {
        const float* W; unsigned short* Wt; int Kd, Nd, n0, k0;
        if (b < 2304) {
            int b2 = b - 2048;
            int which = b2 >> 6, tl = b2 & 63;
            W  = (which == 0) ? Wq : (which == 1) ? Wk : (which == 2) ? Wv : Wo;
            Wt = (which == 0) ? WqT : (which == 1) ? WkT : (which == 2) ? WvT : WoT;
            Kd = 256; Nd = 256;
            n0 = (tl & 7) * 32; k0 = (tl >> 3) * 32;
        } else {
            int b2 = b - 2304;
            W = gaw1; Wt = gaw1T; Kd = 512; Nd = 1024;
            n0 = (b2 & 31) * 32; k0 = (b2 >> 5) * 32;
        }
        int tx = t & 31, ty = t >> 5;
        #pragma unroll
        for (int p = 0; p < 4; ++p)
            tile[ty + p * 8][tx] = W[(k0 + ty + p * 8) * (long)Nd + n0 + tx];
        __syncthreads();
        #pragma unroll
        for (int p = 0; p < 4; ++p)
            Wt[(n0 + ty + p * 8) * (long)Kd + k0 + tx] = f2bf(tile[tx][ty + p * 8]);
    } else {
        if (t < 16) {
            int h = t & 7;
            float x = (t >> 3) ? 1.0f : 0.0f;
            float acc = tb2[h];
            for (int c = 0; c < 32; ++c)
                acc += silu_f(x * tw1[c] + tb1[c]) * tw2[c * 8 + h];
            t01[t] = acc;
        }
    }
}

// ---------------- shared MFMA 64x64 tile ----------------
// A [M][K] bf16 row-major, Bt [N][K] bf16 row-major (B pre-transposed).
// Verified layouts: A[m=lane&15][k=quad*8+j]; B[k=quad*8+j][n=lane&15];
// C/D: col=lane&15, row=quad*4+reg.

__device__ __forceinline__ void mfma_tile64(const unsigned short* __restrict__ A,
                                            const unsigned short* __restrict__ Bt,
                                            int K, int i0, int j0, int t,
                                            f32x4 acc[2][2],
                                            unsigned short* As, unsigned short* Bs) {
    int l = t & 63, w = t >> 6;
    int wi = w >> 1, wj = w & 1;
    int quad = l >> 4, lj = l & 15;
    int sr = t >> 2, skp = (t & 3) * 8;
    f32x4 z = {0.f, 0.f, 0.f, 0.f};
    acc[0][0] = z; acc[0][1] = z; acc[1][0] = z; acc[1][1] = z;
    for (int k0 = 0; k0 < K; k0 += 32) {
        *(int4*)&As[sr * 32 + skp] = *(const int4*)&A[(i0 + sr) * (long)K + k0 + skp];
        *(int4*)&Bs[sr * 32 + skp] = *(const int4*)&Bt[(j0 + sr) * (long)K + k0 + skp];
        __syncthreads();
        short8 a0 = *(short8*)&As[(wi * 32 + lj) * 32 + quad * 8];
        short8 a1 = *(short8*)&As[(wi * 32 + 16 + lj) * 32 + quad * 8];
        short8 b0 = *(short8*)&Bs[(wj * 32 + lj) * 32 + quad * 8];
        short8 b1 = *(short8*)&Bs[(wj * 32 + 16 + lj) * 32 + quad * 8];
        acc[0][0] = __builtin_amdgcn_mfma_f32_16x16x32_bf16(a0, b0, acc[0][0], 0, 0, 0);
        acc[0][1] = __builtin_amdgcn_mfma_f32_16x16x32_bf16(a0, b1, acc[0][1], 0, 0, 0);
        acc[1][0] = __builtin_amdgcn_mfma_f32_16x16x32_bf16(a1, b0, acc[1][0], 0, 0, 0);
        acc[1][1] = __builtin_amdgcn_mfma_f32_16x16x32_bf16(a1, b1, acc[1][1], 0, 0, 0);
        __syncthreads();
    }
}

// ---------------- fused projections: QKV (192 blocks) + gate hidden (256) ----

__global__ __launch_bounds__(256)
void proj_kernel(const unsigned short* __restrict__ src_bf,
                 const unsigned short* __restrict__ tgt_bf,
                 const unsigned short* __restrict__ gateA,
                 const unsigned short* __restrict__ WqT,
                 const unsigned short* __restrict__ WkT,
                 const unsigned short* __restrict__ WvT,
                 const unsigned short* __restrict__ gaw1T,
                 const float* __restrict__ bq, const float* __restrict__ bk,
                 const float* __restrict__ bv, const float* __restrict__ gab1,
                 unsigned short* __restrict__ q_bf, unsigned short* __restrict__ k_bf,
                 float* __restrict__ v_f, float* __restrict__ gh) {
    __shared__ unsigned short As[64 * 32];
    __shared__ unsigned short Bs[64 * 32];
    int b = blockIdx.x, t = threadIdx.x;
    int l = t & 63, w = t >> 6, wi = w >> 1, wjq = w & 1, quad = l >> 4, lj = l & 15;
    f32x4 acc[2][2];
    if (b < 192) {
        int z = b >> 6, rem = b & 63;
        int j0 = (rem & 3) * 64, i0 = (rem >> 2) * 64;
        const unsigned short* A  = (z == 0) ? src_bf : tgt_bf;
        const unsigned short* Bt = (z == 0) ? WqT : (z == 1) ? WkT : WvT;
        const float* bias        = (z == 0) ? bq : (z == 1) ? bk : bv;
        mfma_tile64(A, Bt, HIDD, i0, j0, t, acc, As, Bs);
        unsigned short* obf = (z == 0) ? q_bf : k_bf;
        #pragma unroll
        for (int rg = 0; rg < 2; ++rg)
            #pragma unroll
            for (int cg = 0; cg < 2; ++cg) {
                int col  = j0 + wjq * 32 + cg * 16 + lj;
                int row0 = i0 + wi * 32 + rg * 16 + quad * 4;
                float bb = bias[col];
                #pragma unroll
                for (int r = 0; r < 4; ++r) {
                    float v = acc[rg][cg][r] + bb;
                    if (z < 2) obf[(row0 + r) * HIDD + col] = f2bf(v);
                    else       v_f[(row0 + r) * HIDD + col] = v;
                }
            }
    } else {
        int b2 = b - 192;
        int j0 = (b2 & 15) * 64, i0 = (b2 >> 4) * 64;
        mfma_tile64(gateA, gaw1T, 512, i0, j0, t, acc, As, Bs);
        #pragma unroll
        for (int rg = 0; rg < 2; ++rg)
            #pragma unroll
            for (int cg = 0; cg < 2; ++cg) {
                int col  = j0 + wjq * 32 + cg * 16 + lj;
                int row0 = i0 + wi * 32 + rg * 16 + quad * 4;
                float bb = gab1[col];
                #pragma unroll
                for (int r = 0; r < 4; ++r)
                    gh[(row0 + r) * 1024 + col] = silu_f(acc[rg][cg][r] + bb);
            }
    }
}

// ---------------- gate logits + 2-way softmax ----------------

__global__ __launch_bounds__(256)
void gate_final_kernel(const float* __restrict__ gh, const float* __restrict__ w2,
                       const float* __restrict__ b2, float* __restrict__ gate) {
    __shared__ float w2s[2048];
    __shared__ float red[8];
    int n = blockIdx.x, t = threadIdx.x;
    #pragma unroll
    for (int l = 0; l < 8; ++l) w2s[t + 256 * l] = w2[t + 256 * l];
    __syncthreads();
    float4 x = ((const float4*)(gh + (long)n * 1024))[t];
    float l0 = x.x * w2s[8 * t]     + x.y * w2s[8 * t + 2] +
               x.z * w2s[8 * t + 4] + x.w * w2s[8 * t + 6];
    float l1 = x.x * w2s[8 * t + 1] + x.y * w2s[8 * t + 3] +
               x.z * w2s[8 * t + 5] + x.w * w2s[8 * t + 7];
    #pragma unroll
    for (int off = 32; off > 0; off >>= 1) {
        l0 += __shfl_xor(l0, off, 64);
        l1 += __shfl_xor(l1, off, 64);
    }
    if ((t & 63) == 0) { red[(t >> 6) * 2] = l0; red[(t >> 6) * 2 + 1] = l1; }
    __syncthreads();
    if (t == 0) {
        float L0 = b2[0] + red[0] + red[2] + red[4] + red[6];
        float L1 = b2[1] + red[1] + red[3] + red[5] + red[7];
        float mx = fmaxf(L0, L1);
        float e0 = __expf(L0 - mx), e1 = __expf(L1 - mx);
        float inv = 1.0f / (e0 + e1);
        gate[2 * n]     = e0 * inv;
        gate[2 * n + 1] = e1 * inv;
    }
}

// ---------------- score via MFMA: 64x64 pair blocks, all 8 heads ----------------
// geo table packed [h/2][pair] as dwords -> conflict-free LDS access both ways.

__global__ __launch_bounds__(256)
void score_mfma_kernel(const unsigned short* __restrict__ qbf,
                       const unsigned short* __restrict__ kbf,
                       const float* __restrict__ pos, const float* __restrict__ gate,
                       const unsigned* __restrict__ pbits, const float* __restrict__ t01,
                       const float* __restrict__ gw1, const float* __restrict__ gb1,
                       const float* __restrict__ gw2, const float* __restrict__ gb2,
                       float* __restrict__ S) {
    __shared__ unsigned geo2[4 * 4096];        // 64 KB  [h/2][pair] (lo=2h, hi=2h+1)
    __shared__ float posA[192], posB[192];
    __shared__ unsigned prowL[128];            // [i][word]
    __shared__ float g01[128];
    __shared__ float w1s[32], b1s[32], w2s[256], b2s[8], t01s[16];
    int t  = threadIdx.x;
    int n0 = blockIdx.y * 64, m0 = blockIdx.x * 64;
    w2s[t] = gw2[t];
    if (t < 192) { posA[t] = pos[n0 * 3 + t]; posB[t] = pos[m0 * 3 + t]; }
    if (t < 128) {
        prowL[t] = pbits[(n0 + (t >> 1)) * NW + (m0 >> 5) + (t & 1)];
        g01[t]   = gate[n0 * 2 + t];
    }
    if (t < 32) { w1s[t] = gw1[t]; b1s[t] = gb1[t]; }
    if (t < 16) t01s[t] = t01[t];
    if (t < 8)  b2s[t] = gb2[t];
    __syncthreads();

    // phase 1: geo MLP, 16 pairs per thread
    for (int pp = 0; pp < 16; ++pp) {
        int p = pp * 256 + t;
        int i = p >> 6, j = p & 63;
        float dx = posA[i * 3]     - posB[j * 3];
        float dy = posA[i * 3 + 1] - posB[j * 3 + 1];
        float dz = posA[i * 3 + 2] - posB[j * 3 + 2];
        float dist = sqrtf(fmaxf(dx * dx + dy * dy + dz * dz, 1e-12f));
        float go[8];
        #pragma unroll
        for (int h = 0; h < 8; ++h) go[h] = b2s[h];
        #pragma unroll 4
        for (int c = 0; c < 32; ++c) {
            float hh = silu_f(dist * w1s[c] + b1s[c]);
            #pragma unroll
            for (int h = 0; h < 8; ++h) go[h] += hh * w2s[c * 8 + h];
        }
        #pragma unroll
        for (int h2 = 0; h2 < 4; ++h2)
            geo2[h2 * 4096 + p] = (unsigned)f2bf(go[2 * h2]) |
                                  ((unsigned)f2bf(go[2 * h2 + 1]) << 16);
    }
    __syncthreads();

    // phase 2: wave w owns local rows [w*16, w*16+16), all cols, all heads
    int l = t & 63, w = t >> 6, quad = l >> 4, lj = l & 15;
    const float scale = 0.17677669529663687f;  // 1/sqrt(32)
    for (int h = 0; h < 8; ++h) {
        short8 a = *(const short8*)&qbf[(n0 + w * 16 + lj) * HIDD + h * 32 + quad * 8];
        f32x4 z = {0.f, 0.f, 0.f, 0.f};
        f32x4 acc[4];
        #pragma unroll
        for (int cg = 0; cg < 4; ++cg) {
            short8 bfr = *(const short8*)&kbf[(m0 + cg * 16 + lj) * HIDD + h * 32 + quad * 8];
            acc[cg] = __builtin_amdgcn_mfma_f32_16x16x32_bf16(a, bfr, z, 0, 0, 0);
        }
        #pragma unroll
        for (int cg = 0; cg < 4; ++cg) {
            int j = cg * 16 + lj;
            #pragma unroll
            for (int r = 0; r < 4; ++r) {
                int i = w * 16 + quad * 4 + r;
                unsigned gw2v = geo2[(h >> 1) * 4096 + i * 64 + j];
                float geo_v = bf2f((h & 1) ? (gw2v >> 16) : (gw2v & 0xffffu));
                unsigned bit = (prowL[i * 2 + (j >> 5)] >> (j & 31)) & 1u;
                float val = acc[cg][r] * scale + g01[i * 2] * geo_v +
                            g01[i * 2 + 1] * t01s[bit * 8 + h];
                S[((long)h << 20) + (n0 + i) * NN + m0 + j] = val;
            }
        }
    }
}

// ---------------- softmax + PV, 8 rows per block; bf16 output ----------------

#define RG 8

__global__ __launch_bounds__(256)
void softpv_kernel(const float* __restrict__ S, const float* __restrict__ v,
                   unsigned short* __restrict__ out_bf) {
    __shared__ float sr[RG][NN];        // 32 KB
    __shared__ float part[8][RG][32];   // 8 KB
    __shared__ float invs[RG];
    int h  = blockIdx.x;
    int n0 = blockIdx.y * RG;
    int t  = threadIdx.x;
    const float4* S4 = (const float4*)(S + ((long)h << 20) + (long)n0 * NN);
    #pragma unroll
    for (int r = 0; r < RG; ++r)
        ((float4*)sr[r])[t] = S4[r * 256 + t];
    __syncthreads();
    {   // softmax: wave wv handles rows wv and wv+4
        int wv = t >> 6, l = t & 63;
        #pragma unroll
        for (int rr = 0; rr < 2; ++rr) {
            int r = wv + rr * 4;
            float mx = -1e30f;
            #pragma unroll 4
            for (int m = l; m < NN; m += 64) mx = fmaxf(mx, sr[r][m]);
            #pragma unroll
            for (int off = 32; off > 0; off >>= 1) mx = fmaxf(mx, __shfl_xor(mx, off, 64));
            float sum = 0.0f;
            #pragma unroll 4
            for (int m = l; m < NN; m += 64) {
                float e = __expf(sr[r][m] - mx);
                sr[r][m] = e;
                sum += e;
            }
            #pragma unroll
            for (int off = 32; off > 0; off >>= 1) sum += __shfl_xor(sum, off, 64);
            if (l == 0) invs[r] = 1.0f / sum;
        }
    }
    __syncthreads();
    {   // PV: thread (chunk, d); 128 m per chunk
        int dd = t & 31, ch = t >> 5;
        float acc[RG] = {};
        const float* vp = v + (ch * 128) * HIDD + h * 32 + dd;
        #pragma unroll 4
        for (int i = 0; i < 128; ++i) {
            float vv = vp[i * HIDD];
            int m = ch * 128 + i;
            #pragma unroll
            for (int r = 0; r < RG; ++r) acc[r] += sr[r][m] * vv;
        }
        #pragma unroll
        for (int r = 0; r < RG; ++r) part[ch][r][dd] = acc[r];
    }
    __syncthreads();
    {
        int r = t >> 5, d2 = t & 31;
        float s = 0.0f;
        #pragma unroll
        for (int c = 0; c < 8; ++c) s += part[c][r][d2];
        out_bf[(n0 + r) * HIDD + h * 32 + d2] = f2bf(s * invs[r]);
    }
}

// ---------------- fused Wo projection + residual + LayerNorm ----------------
// 64 blocks; block handles 16 rows x 256 cols. A staged in LDS; wave w owns
// 64-col strip. LN epilogue in-block.

__global__ __launch_bounds__(256)
void wo_ln_kernel(const unsigned short* __restrict__ aout_bf,
                  const unsigned short* __restrict__ WoT,
                  const float* __restrict__ bo, const float* __restrict__ xres,
                  const float* __restrict__ lng, const float* __restrict__ lnb,
                  float* __restrict__ out) {
    __shared__ unsigned short Asm[16 * 264];   // padded: row stride 264
    __shared__ float Osm[16][260];             // padded
    __shared__ float Lg[256], Lb[256];
    int t = threadIdx.x;
    int r0 = blockIdx.x * 16;
    Lg[t] = lng[t]; Lb[t] = lnb[t];
    // stage A [16][256] bf16
    #pragma unroll
    for (int c = 0; c < 2; ++c) {
        int chunk = t * 2 + c;                 // 512 chunks of 8 ushorts
        int row = chunk >> 5, off = (chunk & 31) * 8;
        *(int4*)&Asm[row * 264 + off] = *(const int4*)&aout_bf[(r0 + row) * HIDD + off];
    }
    __syncthreads();
    int l = t & 63, w = t >> 6, quad = l >> 4, lj = l & 15;
    f32x4 z = {0.f, 0.f, 0.f, 0.f};
    f32x4 acc[4] = {z, z, z, z};
    for (int ks = 0; ks < 8; ++ks) {
        short8 a = *(short8*)&Asm[lj * 264 + ks * 32 + quad * 8];
        #pragma unroll
        for (int nt = 0; nt < 4; ++nt) {
            int col = w * 64 + nt * 16 + lj;
            short8 bfr = *(const short8*)&WoT[col * HIDD + ks * 32 + quad * 8];
            acc[nt] = __builtin_amdgcn_mfma_f32_16x16x32_bf16(a, bfr, acc[nt], 0, 0, 0);
        }
    }
    #pragma unroll
    for (int nt = 0; nt < 4; ++nt) {
        int col = w * 64 + nt * 16 + lj;
        float bb = bo[col];
        #pragma unroll
        for (int r = 0; r < 4; ++r)
            Osm[quad * 4 + r][col] = acc[nt][r] + bb;
    }
    __syncthreads();
    // LN: wave w handles rows w*4 .. w*4+3; lane l covers cols l*4..l*4+3
    #pragma unroll
    for (int rr = 0; rr < 4; ++rr) {
        int row = w * 4 + rr;
        float4 o  = *(float4*)&Osm[row][l * 4];
        float4 s4 = *(const float4*)&xres[(r0 + row) * HIDD + l * 4];
        float x0 = o.x + s4.x, x1 = o.y + s4.y, x2 = o.z + s4.z, x3 = o.w + s4.w;
        float sum = x0 + x1 + x2 + x3;
        float ss  = x0 * x0 + x1 * x1 + x2 * x2 + x3 * x3;
        #pragma unroll
        for (int off = 32; off > 0; off >>= 1) {
            sum += __shfl_xor(sum, off, 64);
            ss  += __shfl_xor(ss,  off, 64);
        }
        float mean = sum * (1.0f / HIDD);
        float var  = ss * (1.0f / HIDD) - mean * mean;
        float rstd = rsqrtf(var + 1e-5f);
        float4 ov;
        ov.x = (x0 - mean) * rstd * Lg[l * 4]     + Lb[l * 4];
        ov.y = (x1 - mean) * rstd * Lg[l * 4 + 1] + Lb[l * 4 + 1];
        ov.z = (x2 - mean) * rstd * Lg[l * 4 + 2] + Lb[l * 4 + 2];
        ov.w = (x3 - mean) * rstd * Lg[l * 4 + 3] + Lb[l * 4 + 3];
        *(float4*)&out[(r0 + row) * HIDD + l * 4] = ov;
    }
}

// ---------------- host ----------------

extern "C" void kernel_launch(void* const* d_in, const int* in_sizes, int n_in,
                              void* d_out, int out_size, void* d_ws, size_t ws_size,
                              hipStream_t stream) {
    const float* src  = (const float*)d_in[0];
    const float* tgt  = (const float*)d_in[1];
    const float* pos  = (const float*)d_in[2];
    const int*   ei   = (const int*)d_in[3];
    const float* Wq   = (const float*)d_in[4];  const float* bq  = (const float*)d_in[5];
    const float* Wk   = (const float*)d_in[6];  const float* bk  = (const float*)d_in[7];
    const float* Wv   = (const float*)d_in[8];  const float* bv  = (const float*)d_in[9];
    const float* gw1  = (const float*)d_in[10]; const float* gb1 = (const float*)d_in[11];
    const float* gw2  = (const float*)d_in[12]; const float* gb2 = (const float*)d_in[13];
    const float* tw1  = (const float*)d_in[14]; const float* tb1 = (const float*)d_in[15];
    const float* tw2  = (const float*)d_in[16]; const float* tb2 = (const float*)d_in[17];
    const float* gaw1 = (const float*)d_in[18]; const float* gab1= (const float*)d_in[19];
    const float* gaw2 = (const float*)d_in[20]; const float* gab2= (const float*)d_in[21];
    const float* Wo   = (const float*)d_in[22]; const float* bo  = (const float*)d_in[23];
    const float* lng  = (const float*)d_in[24]; const float* lnb = (const float*)d_in[25];
    int E = in_sizes[3] / 2;

    char* w = (char*)d_ws;
    unsigned* acol = (unsigned*)w; w += NN * NW * 4;
    unsigned* p0   = (unsigned*)w; w += NN * NW * 4;   // contiguous with acol
    unsigned* p1   = (unsigned*)w; w += NN * NW * 4;
    unsigned short* src_bf = (unsigned short*)w; w += NN * HIDD * 2;
    unsigned short* tgt_bf = (unsigned short*)w; w += NN * HIDD * 2;
    unsigned short* gateA  = (unsigned short*)w; w += NN * 512 * 2;
    unsigned short* WqT    = (unsigned short*)w; w += HIDD * HIDD * 2;
    unsigned short* WkT    = (unsigned short*)w; w += HIDD * HIDD * 2;
    unsigned short* WvT    = (unsigned short*)w; w += HIDD * HIDD * 2;
    unsigned short* WoT    = (unsigned short*)w; w += HIDD * HIDD * 2;
    unsigned short* gaw1T  = (unsigned short*)w; w += 1024 * 512 * 2;
    unsigned short* q_bf   = (unsigned short*)w; w += NN * HIDD * 2;
    unsigned short* k_bf   = (unsigned short*)w; w += NN * HIDD * 2;
    float* v_f  = (float*)w; w += NN * HIDD * 4;
    float* gh   = (float*)w; w += (long)NN * 1024 * 4;  // 4 MB
    float* gate = (float*)w; w += NN * 2 * 4;
    float* t01  = (float*)w; w += 256;
    unsigned short* aout_bf = (unsigned short*)w; w += NN * HIDD * 2;
    float* S    = (float*)w; w += (long)NH * NN * NN * 4;  // 32 MB

    // adjacency bits
    hipMemsetAsync(acol, 0, 2 * NN * NW * 4, stream);
    scatter_edges_kernel<<<(E + 255) / 256, 256, 0, stream>>>(ei, E, p0, acol);

    // prep (converts + transposes + topo) — independent of path
    prep_kernel<<<2817, 256, 0, stream>>>(src, tgt, Wq, Wk, Wv, Wo, gaw1,
                                          tw1, tb1, tw2, tb2,
                                          src_bf, tgt_bf, gateA,
                                          WqT, WkT, WvT, WoT, gaw1T, t01);

    path_iter_kernel<<<NN / 8, 256, 0, stream>>>(p0, acol, p1);
    path_iter_kernel<<<NN / 8, 256, 0, stream>>>(p1, acol, p0);
    path_iter_kernel<<<NN / 8, 256, 0, stream>>>(p0, acol, p1);   // final path in p1

    // projections: QKV + gate hidden in one launch
    proj_kernel<<<448, 256, 0, stream>>>(src_bf, tgt_bf, gateA, WqT, WkT, WvT, gaw1T,
                                         bq, bk, bv, gab1, q_bf, k_bf, v_f, gh);
    gate_final_kernel<<<NN, 256, 0, stream>>>(gh, gaw2, gab2, gate);

    // scores (MFMA + fused bias) -> softmax+PV
    score_mfma_kernel<<<dim3(16, 16), 256, 0, stream>>>(q_bf, k_bf, pos, gate, p1, t01,
                                                        gw1, gb1, gw2, gb2, S);
    softpv_kernel<<<dim3(NH, NN / RG), 256, 0, stream>>>(S, v_f, aout_bf);

    // Wo projection + residual + LN fused
    wo_ln_kernel<<<NN / 16, 256, 0, stream>>>(aout_bf, WoT, bo, src, lng, lnb,
                                              (float*)d_out);
}